// Round 5
// baseline (294.600 us; speedup 1.0000x reference)
//
#include <hip/hip_runtime.h>
#include <stdint.h>

#define BB 4
#define SDIM 128
#define S2 (SDIM*SDIM)          // 16384
#define S3 ((size_t)SDIM*S2)    // 2097152

// Per-wave probe: detect bool storage width (1B vs 4B) from structure
// (valid is a prefix of >=64 trues; element S-1 is always false), then
// return len[b] = popcount of the valid prefix. All 64 lanes participate.
__device__ __forceinline__ int probe_len(const void* em, int b, int lane) {
    const unsigned char* p8 = (const unsigned char*)em;
    const int* p32 = (const int*)em;
    const int t0 = lane, t1 = lane + 64;
    const size_t i0 = (size_t)b*S2 + (size_t)t0*SDIM + t0;
    const size_t i1 = (size_t)b*S2 + (size_t)t1*SDIM + t1;
    const unsigned char a0 = p8[i0], a1 = p8[i1];
    const bool ok = (a0 != 0) && (t1 != SDIM-1 || a1 == 0);
    const unsigned long long mok = __ballot(ok);
    const bool use8 = (mok == ~0ull);   // wave-uniform
    int v0, v1;
    if (use8) { v0 = (a0 != 0); v1 = (a1 != 0); }
    else      { v0 = (p32[i0] != 0); v1 = (p32[i1] != 0); }
    return __popcll(__ballot(v0)) + __popcll(__ballot(v1));
}

__device__ __forceinline__ float sigf(float x) { return 1.f / (1.f + expf(-x)); }

// Fire-and-forget global->LDS copy: 64 lanes x 16B. No VGPR destination =>
// the scheduler has NOTHING to serialize on; all issued loads stay in flight
// until the single vmcnt drain at __syncthreads(). This is the MLP mechanism
// rounds 2-4 failed to get from VGPR loads (compiler always re-serialized).
// LDS dest = wave-uniform base + lane*16; global src is per-lane.
__device__ __forceinline__ void gll16(const float* g, float* l) {
    __builtin_amdgcn_global_load_lds(
        (const __attribute__((address_space(1))) void*)g,
        (__attribute__((address_space(3))) void*)l, 16, 0, 0);
}

// Fused: q/sigmoid init + splitsum partials via LDS staging.
// Grid (B*S, 2): y splits the j-reduction strips. Up to 8 gll per wave,
// one barrier, then LDS reduce.
__global__ __launch_bounds__(256) void k_prep(
    const float* __restrict__ s_edge, const float* __restrict__ s_const,
    const float* __restrict__ s_split, const void* __restrict__ em,
    float* __restrict__ q_edge, float* __restrict__ q_span,
    float* __restrict__ split0, float* __restrict__ split1,
    float* __restrict__ peA, float* __restrict__ peB,
    float* __restrict__ peTA, float* __restrict__ peTB,
    float* __restrict__ psA, float* __restrict__ psB) {
    __shared__ float plds[64*SDIM];     // 32 KB: up to 64 staged rows
    __shared__ float red2[2][SDIM];
    const int b = blockIdx.x >> 7, i = blockIdx.x & 127;
    const int y = blockIdx.y;
    const int tid = threadIdx.x, lane = tid & 63, wave = tid >> 6;
    const int len = probe_len(em, b, lane);
    const int lm1 = len - 1;
    const size_t vb = (size_t)b*S2;
    if (y == 0 && tid < SDIM) {
        const size_t ro = vb + (size_t)i*SDIM + tid;
        const float qe = s_edge[ro];
        const float qs = (i <= tid) ? s_const[ro] : s_const[vb + (size_t)tid*SDIM + i];
        q_edge[ro] = qe;
        q_span[ro] = qs;
        const float se = sigf(qe), ss = sigf(qs);
        peA[ro] = se; peB[ro] = se;
        psA[ro] = ss; psB[ro] = ss;
        const size_t to = vb + (size_t)tid*SDIM + i;
        peTA[to] = se; peTB[to] = se;
    }
    // Stage rows j = i + 2*(y+2*mloc) + {0,1} into LDS rows 2*mloc, 2*mloc+1.
    if (i >= 1 && i < len) {
        const int L = len - i;
        const float* sb = s_split + (size_t)b*S3 + (size_t)i*S2;
        for (int mloc = wave; mloc < 32; mloc += 4) {
            const int t0 = 2*(y + 2*mloc);
            if (t0 >= L) break;                    // wave-uniform
            const int j = i + t0 + (lane >> 5);
            const int jc = min(j, lm1);
            gll16(sb + (size_t)jc*SDIM + (lane & 31)*4, &plds[(2*mloc)*SDIM]);
        }
    }
    __syncthreads();   // drains vmcnt(0): ALL staged loads were in flight together
    const int k = tid & 127, rh = tid >> 7;
    float sum = 0.f;
    #pragma unroll
    for (int u = 0; u < 32; ++u) {
        const int r = rh + 2*u;
        const int j = i + 4*u + 2*y + rh;          // j of LDS row r
        sum += (j < len && j != k) ? plds[r*SDIM + k] : 0.f;
    }
    red2[rh][k] = sum;
    __syncthreads();
    if (tid < SDIM) {
        float* out = y ? split1 : split0;
        out[vb + (size_t)i*SDIM + tid] =
            (i >= 1 && i < len && tid >= 1 && tid < len)
            ? (red2[0][tid] + red2[1][tid]) : 0.f;
    }
}

// Fused per-iteration update, v6: LDS-staged via global_load_lds.
// Grid (B*S, 16): y<8 edge (m-chunk of 16 rows), y>=8 span (j-chunk of 16).
// Per block: stage 6 (edge) / 3 (span) surfaces x 16 rows x 512B into LDS
// (12 / 6 gll per wave, all in flight), wave0 batch-loads per-row scalars
// into sml[], ONE barrier, then compute from LDS. Masks/arithmetic identical
// to the passing round-4 kernel. Sigmoid ping-pong epilogue unchanged.
__global__ __launch_bounds__(256) void k_upd(
    const float* __restrict__ s_sib, const float* __restrict__ s_cop,
    const float* __restrict__ s_grd, const float* __restrict__ s_ep,
    const float* __restrict__ s_hb,  const float* __restrict__ s_he,
    const float* __restrict__ peA, const float* __restrict__ peTA,
    const float* __restrict__ psA,
    const float* __restrict__ split0, const float* __restrict__ split1,
    const void* __restrict__ em,
    float* __restrict__ q_edge, float* __restrict__ q_span,
    float* __restrict__ peB, float* __restrict__ peTB, float* __restrict__ psB) {
    __shared__ float lds[6*16*SDIM];   // 48 KB
    __shared__ float sml[64];          // per-row scalars, staged by wave 0
    const int b = blockIdx.x >> 7, row = blockIdx.x & 127;
    const int tid = threadIdx.x, wave = tid >> 6, lane = tid & 63;
    const int half = lane >> 5, sq = (lane & 31) * 4;
    const int len = probe_len(em, b, lane);
    const int lm1 = len - 1;
    const size_t vb = (size_t)b*S2;

    if (blockIdx.y < 8) {
        const int h = row;
        const int m0 = blockIdx.y * 16;
        if (h >= len || m0 >= len) return;
        const size_t tb = (size_t)b*S3 + (size_t)h*S2;
        const size_t hrow = vb + (size_t)h*SDIM;
        const float* bases[6] = { s_sib + tb, s_cop + tb, s_grd + tb,
                                  s_ep + tb,  peTA + vb,  psA + vb };
        #pragma unroll
        for (int T = 0; T < 6; ++T) {
            #pragma unroll
            for (int ss = 0; ss < 2; ++ss) {
                const int s  = 2*wave + ss;        // strip 0..7 (wave-uniform)
                const int r2 = 2*s + half;         // row in tile 0..15
                const int mc = min(m0 + r2, lm1);  // clamped global row
                gll16(bases[T] + (size_t)mc*SDIM + sq, &lds[(T*16 + 2*s)*SDIM]);
            }
        }
        if (tid < 16)   // batch the per-row q_edge scalars (one load per lane)
            sml[tid] = q_edge[hrow + min(m0 + tid, lm1)];
        __syncthreads();   // one vmcnt(0) drain for everything
        const float4 pe4 = *(const float4*)(peA + hrow + sq);
        #pragma unroll
        for (int it = 0; it < 2; ++it) {
            const int m = m0 + it*8 + wave*2 + half;
            const int r = it*8 + wave*2 + half;    // LDS tile row
            const float4 sibv = *(const float4*)&lds[(0*16 + r)*SDIM + sq];
            const float4 copv = *(const float4*)&lds[(1*16 + r)*SDIM + sq];
            const float4 grdv = *(const float4*)&lds[(2*16 + r)*SDIM + sq];
            const float4 epvv = *(const float4*)&lds[(3*16 + r)*SDIM + sq];
            const float4 petv = *(const float4*)&lds[(4*16 + r)*SDIM + sq];
            const float4 psvv = *(const float4*)&lds[(5*16 + r)*SDIM + sq];
            const bool mv = (m < len);
            float rr = 0.f;
            #define TERM(C, F) { const int s = sq + C;                               \
                const bool bs = mv && (s < len) && (m != s);                         \
                const float fem = (bs && (h != s)) ? 1.f : 0.f;                      \
                const float fnc = (bs && ((m >= h && s >= h) || (m <= h && s <= h))) \
                                  ? 1.f : 0.f;                                       \
                rr += fem * (sibv.F*pe4.F + copv.F*petv.F + grdv.F*psvv.F)           \
                    + fnc * (epvv.F*psvv.F); }
            TERM(0, x) TERM(1, y) TERM(2, z) TERM(3, w)
            #undef TERM
            rr += __shfl_xor(rr, 16); rr += __shfl_xor(rr, 8); rr += __shfl_xor(rr, 4);
            rr += __shfl_xor(rr, 2);  rr += __shfl_xor(rr, 1);
            if ((lane & 31) == 0 && mv) {
                const float qn = sml[r] + rr;
                q_edge[hrow + m] = qn;
                const float sg = sigf(qn);
                peB[hrow + m] = sg;
                peTB[vb + (size_t)m*SDIM + h] = sg;
            }
        }
    } else {
        const int i = row;
        const int j0 = (blockIdx.y - 8) * 16;
        if (i < 1 || i >= len || j0 >= len) return;
        const size_t irow = vb + (size_t)i*SDIM;
        #pragma unroll
        for (int ss = 0; ss < 2; ++ss) {
            const int s  = 2*wave + ss;
            const int r2 = 2*s + half;
            const int jc = min(j0 + r2, lm1);
            gll16(s_hb + (size_t)b*S3 + (size_t)i*S2 + (size_t)jc*SDIM + sq,
                  &lds[(0*16 + 2*s)*SDIM]);
            gll16(s_he + (size_t)b*S3 + (size_t)jc*S2 + (size_t)i*SDIM + sq,
                  &lds[(1*16 + 2*s)*SDIM]);
            gll16(peTA + vb + (size_t)jc*SDIM + sq,
                  &lds[(2*16 + 2*s)*SDIM]);
        }
        if (tid < 64) {   // batch per-row scalars: 4 surfaces x 16 rows
            const int surf = tid >> 4, jj = tid & 15;
            const int jc = min(j0 + jj, lm1);
            const size_t o = irow + jc;
            const float v = (surf == 0) ? q_span[o]
                          : (surf == 1) ? psA[o]
                          : (surf == 2) ? split0[o] : split1[o];
            sml[tid] = v;
        }
        __syncthreads();
        const float4 peTi4 = *(const float4*)(peTA + irow + sq);
        #pragma unroll
        for (int it = 0; it < 2; ++it) {
            const int j = j0 + it*8 + wave*2 + half;
            const int r = it*8 + wave*2 + half;
            const float4 hbv  = *(const float4*)&lds[(0*16 + r)*SDIM + sq];
            const float4 hev  = *(const float4*)&lds[(1*16 + r)*SDIM + sq];
            const float4 ptjv = *(const float4*)&lds[(2*16 + r)*SDIM + sq];
            const bool act = (j > i) && (j < len);
            float rr = 0.f;
            #define TERM(C, F) { const int s = sq + C;                               \
                const float f = (act && s >= 1 && s < len && (s < i || s > j))       \
                                ? 1.f : 0.f;                                         \
                rr += f * (hbv.F*peTi4.F + hev.F*ptjv.F); }
            TERM(0, x) TERM(1, y) TERM(2, z) TERM(3, w)
            #undef TERM
            rr += __shfl_xor(rr, 16); rr += __shfl_xor(rr, 8); rr += __shfl_xor(rr, 4);
            rr += __shfl_xor(rr, 2);  rr += __shfl_xor(rr, 1);
            if ((lane & 31) == 0 && j >= 1 && j < len) {
                const float qn = sml[r] + rr + sml[16 + r] * (sml[32 + r] + sml[48 + r]);
                q_span[irow + j] = qn;
                psB[irow + j] = sigf(qn);
            }
        }
    }
}

extern "C" void kernel_launch(void* const* d_in, const int* in_sizes, int n_in,
                              void* d_out, int out_size, void* d_ws, size_t ws_size,
                              hipStream_t stream) {
    const float* s_edge  = (const float*)d_in[0];
    const float* s_const = (const float*)d_in[1];
    const float* s_sib   = (const float*)d_in[2];
    const float* s_cop   = (const float*)d_in[3];
    const float* s_grd   = (const float*)d_in[4];
    const float* s_ep    = (const float*)d_in[5];
    const float* s_split = (const float*)d_in[6];
    const float* s_hb    = (const float*)d_in[7];
    const float* s_he    = (const float*)d_in[8];
    const void*  em      = d_in[9];
    (void)in_sizes; (void)n_in; (void)out_size; (void)ws_size;

    float* q_edge = (float*)d_out;
    float* q_span = q_edge + (size_t)BB * S2;

    char* ws = (char*)d_ws;
    const size_t SZ = (size_t)BB * S2 * sizeof(float);   // 256 KiB
    float* split0 = (float*)(ws);
    float* split1 = (float*)(ws + 1*SZ);
    float* peA    = (float*)(ws + 2*SZ);
    float* peTA   = (float*)(ws + 3*SZ);
    float* psA    = (float*)(ws + 4*SZ);
    float* peB    = (float*)(ws + 5*SZ);
    float* peTB   = (float*)(ws + 6*SZ);
    float* psB    = (float*)(ws + 7*SZ);

    const int NB = BB * SDIM;  // 512
    hipLaunchKernelGGL(k_prep, dim3(NB, 2), dim3(256), 0, stream,
                       s_edge, s_const, s_split, em, q_edge, q_span,
                       split0, split1, peA, peB, peTA, peTB, psA, psB);
    for (int it = 0; it < 3; ++it) {
        const int s = it & 1;
        const float* peR  = s ? peB  : peA;
        const float* peTR = s ? peTB : peTA;
        const float* psR  = s ? psB  : psA;
        float* peW  = s ? peA  : peB;
        float* peTW = s ? peTA : peTB;
        float* psW  = s ? psA  : psB;
        hipLaunchKernelGGL(k_upd, dim3(dim3(NB, 16)), dim3(256), 0, stream,
                           s_sib, s_cop, s_grd, s_ep, s_hb, s_he,
                           peR, peTR, psR, split0, split1, em,
                           q_edge, q_span, peW, peTW, psW);
    }
}